// Round 1
// 2214.773 us; speedup vs baseline: 1.0739x; 1.0739x over previous
//
#include <hip/hip_runtime.h>
#include <math.h>

#define IN_DIM 1024
#define M_DIM  256
#define R_TOT  32768          // B*S = 8*4096
#define TM     32             // rows per block
#define KB     16             // k-chunk for phase 1
#define EPS    1e-12f

// ---------------------------------------------------------------------------
// Fused POVM kernel. Round 1 change: phase-1 basis tile LDS layout.
//
// OLD: sBig[kk][m][2] interleaved re/im -> lane tm's float4 reads had 64 B
//      lane stride -> 16-way bank conflict (measured: 2.58e8 conflict cycles,
//      15.4 extra cyc per ds_read_b128 = exact 16-way serialization).
// NEW: per kk row of 512 floats, 4 planes of 128 floats:
//        plane 0: re of m with m%8<4   plane 1: re of m with m%8>=4
//        plane 2: im of m with m%8<4   plane 3: im of m with m%8>=4
//      within a plane, chunk c (4 floats) holds m = 8c..8c+3 (or +4..+7),
//      stored at chunk position c ^ (2*plane)  (XOR spreads staging writes).
//      Lane tm reads plane p at float offset p*128 + 4*(tm^(2p)):
//      16 B lane stride -> all 32 banks at uniform depth 4 = bandwidth floor.
// Everything else (phases 2-4, output guards, launch) unchanged.
// ---------------------------------------------------------------------------
__global__ __launch_bounds__(256) void povm_kernel(
    const float* __restrict__ psi_re, const float* __restrict__ psi_im,
    const float* __restrict__ basis_re, const float* __restrict__ basis_im,
    float* __restrict__ out,
    long long off_im,       // float offset of imag plane (== off_probs if none)
    long long off_probs,    // float offset of probs chunk
    long long cap)          // total float capacity (= out_size)
{
    __shared__ __align__(16) float sPsi[KB][TM][2];      // 4 KB
    __shared__ __align__(16) float sBig[KB * M_DIM * 2]; // 32 KB; basis tile, then probs[TM][M]
    __shared__ __align__(16) float sScale[TM];

    const int tid  = threadIdx.x;
    const int tr   = tid >> 5;          // 0..7  -> rows 4*tr..4*tr+3
    const int tm   = tid & 31;          // 0..31 -> cols 8*tm..8*tm+7
    const int row0 = blockIdx.x * TM;

    float accRe[4][8];
    float accIm[4][8];
    #pragma unroll
    for (int a = 0; a < 4; ++a)
        #pragma unroll
        for (int b = 0; b < 8; ++b) { accRe[a][b] = 0.f; accIm[a][b] = 0.f; }

    // -------- phase 1: inner GEMM --------
    const int p_arr = tid >> 7;             // 0=re, 1=im
    const int p_row = (tid >> 2) & 31;
    const int p_kq  = tid & 3;
    const float* p_src  = p_arr ? psi_im : psi_re;
    const float* p_base = p_src + (size_t)(row0 + p_row) * IN_DIM + p_kq * 4;
    const int b_kq = tid & 3;
    const int b_m0 = tid >> 2;              // 0..63

    for (int kc = 0; kc < IN_DIM; kc += KB) {
        float4 pv = *(const float4*)(p_base + kc);
        sPsi[p_kq * 4 + 0][p_row][p_arr] = pv.x;
        sPsi[p_kq * 4 + 1][p_row][p_arr] = pv.y;
        sPsi[p_kq * 4 + 2][p_row][p_arr] = pv.z;
        sPsi[p_kq * 4 + 3][p_row][p_arr] = pv.w;
        #pragma unroll
        for (int j = 0; j < 4; ++j) {
            const int m = b_m0 + 64 * j;
            const float4 vr = *(const float4*)(basis_re + (size_t)m * IN_DIM + kc + b_kq * 4);
            const float4 vi = *(const float4*)(basis_im + (size_t)m * IN_DIM + kc + b_kq * 4);
            const int rr = (m >> 2) & 1;                       // re plane 0/1
            const int ch = m >> 3;                             // chunk 0..31
            const int el = m & 3;                              // elem in chunk
            const int pos_re = rr * 128 + ((ch ^ (2 * rr)) << 2) + el;
            const int pos_im = (rr + 2) * 128 + ((ch ^ (2 * (rr + 2))) << 2) + el;
            const int kb0 = b_kq * 4;
            sBig[(kb0 + 0) * 512 + pos_re] = vr.x;
            sBig[(kb0 + 1) * 512 + pos_re] = vr.y;
            sBig[(kb0 + 2) * 512 + pos_re] = vr.z;
            sBig[(kb0 + 3) * 512 + pos_re] = vr.w;
            sBig[(kb0 + 0) * 512 + pos_im] = vi.x;
            sBig[(kb0 + 1) * 512 + pos_im] = vi.y;
            sBig[(kb0 + 2) * 512 + pos_im] = vi.z;
            sBig[(kb0 + 3) * 512 + pos_im] = vi.w;
        }
        __syncthreads();
        #pragma unroll
        for (int kk = 0; kk < KB; ++kk) {
            const float4 pa = *(const float4*)&sPsi[kk][4 * tr][0];
            const float4 pb = *(const float4*)&sPsi[kk][4 * tr + 2][0];
            const float4 r0 = *(const float4*)&sBig[kk * 512 +       4 * tm];
            const float4 r1 = *(const float4*)&sBig[kk * 512 + 128 + 4 * (tm ^ 2)];
            const float4 i0 = *(const float4*)&sBig[kk * 512 + 256 + 4 * (tm ^ 4)];
            const float4 i1 = *(const float4*)&sBig[kk * 512 + 384 + 4 * (tm ^ 6)];
            const float pr[4] = {pa.x, pa.z, pb.x, pb.z};
            const float pi[4] = {pa.y, pa.w, pb.y, pb.w};
            const float rv[8] = {r0.x, r0.y, r0.z, r0.w, r1.x, r1.y, r1.z, r1.w};
            const float iv[8] = {i0.x, i0.y, i0.z, i0.w, i1.x, i1.y, i1.z, i1.w};
            #pragma unroll
            for (int a = 0; a < 4; ++a)
                #pragma unroll
                for (int b = 0; b < 8; ++b) {
                    accRe[a][b] = fmaf(pr[a], rv[b], fmaf(pi[a], iv[b], accRe[a][b]));
                    accIm[a][b] = fmaf(pi[a], rv[b], fmaf(-pr[a], iv[b], accIm[a][b]));
                }
        }
        __syncthreads();
    }

    // -------- phase 2: p = |inner|^2, probs --------
    float rowsum[4] = {0.f, 0.f, 0.f, 0.f};
    #pragma unroll
    for (int a = 0; a < 4; ++a)
        #pragma unroll
        for (int b = 0; b < 8; ++b) {
            const float p = accRe[a][b] * accRe[a][b] + accIm[a][b] * accIm[a][b];
            accRe[a][b] = p;
            rowsum[a] += p;
        }
    #pragma unroll
    for (int off = 1; off < 32; off <<= 1) {
        #pragma unroll
        for (int a = 0; a < 4; ++a)
            rowsum[a] += __shfl_xor(rowsum[a], off, 64);
    }
    float* sProbs = sBig;               // aliased: [TM][M_DIM]
    #pragma unroll
    for (int a = 0; a < 4; ++a) {
        const float inv = 1.f / (rowsum[a] + EPS);
        #pragma unroll
        for (int b = 0; b < 8; ++b) accRe[a][b] *= inv;   // accRe = probs
        const int row = 4 * tr + a;
        const float4 q0 = make_float4(accRe[a][0], accRe[a][1], accRe[a][2], accRe[a][3]);
        const float4 q1 = make_float4(accRe[a][4], accRe[a][5], accRe[a][6], accRe[a][7]);
        *(float4*)&sProbs[row * M_DIM + 8 * tm + 0] = q0;
        *(float4*)&sProbs[row * M_DIM + 8 * tm + 4] = q1;
        const long long po = off_probs + (long long)(row0 + row) * M_DIM + 8 * tm;
        if (po + 8 <= cap) {
            *(float4*)(out + po)     = q0;
            *(float4*)(out + po + 4) = q1;
        }
    }
    __syncthreads();

    // -------- phase 3: collapsed_unscaled = probs @ basis, accumulate normsq --------
    float nsq[4] = {0.f, 0.f, 0.f, 0.f};
    for (int ic = 0; ic < 4; ++ic) {
        #pragma unroll
        for (int a = 0; a < 4; ++a)
            #pragma unroll
            for (int b = 0; b < 8; ++b) { accRe[a][b] = 0.f; accIm[a][b] = 0.f; }
        const int i0 = ic * 256 + 8 * tm;
        for (int m = 0; m < M_DIM; ++m) {
            const float* brp = basis_re + (size_t)m * IN_DIM + i0;
            const float* bip = basis_im + (size_t)m * IN_DIM + i0;
            const float4 br0 = *(const float4*)(brp);
            const float4 br1 = *(const float4*)(brp + 4);
            const float4 bi0 = *(const float4*)(bip);
            const float4 bi1 = *(const float4*)(bip + 4);
            const float rv[8] = {br0.x, br0.y, br0.z, br0.w, br1.x, br1.y, br1.z, br1.w};
            const float iv[8] = {bi0.x, bi0.y, bi0.z, bi0.w, bi1.x, bi1.y, bi1.z, bi1.w};
            float pvv[4];
            #pragma unroll
            for (int a = 0; a < 4; ++a) pvv[a] = sProbs[(4 * tr + a) * M_DIM + m];
            #pragma unroll
            for (int a = 0; a < 4; ++a)
                #pragma unroll
                for (int b = 0; b < 8; ++b) {
                    accRe[a][b] = fmaf(pvv[a], rv[b], accRe[a][b]);
                    accIm[a][b] = fmaf(pvv[a], iv[b], accIm[a][b]);
                }
        }
        #pragma unroll
        for (int a = 0; a < 4; ++a) {
            const int row = 4 * tr + a;
            #pragma unroll
            for (int b = 0; b < 8; ++b)
                nsq[a] += accRe[a][b] * accRe[a][b] + accIm[a][b] * accIm[a][b];
            const long long o = (long long)(row0 + row) * IN_DIM + i0;
            if (o + 8 <= off_im) {                 // real plane region
                *(float4*)(out + o)     = make_float4(accRe[a][0], accRe[a][1], accRe[a][2], accRe[a][3]);
                *(float4*)(out + o + 4) = make_float4(accRe[a][4], accRe[a][5], accRe[a][6], accRe[a][7]);
            }
            const long long oi = off_im + o;
            if (oi + 8 <= off_probs) {             // imag plane region (may be width 0)
                *(float4*)(out + oi)     = make_float4(accIm[a][0], accIm[a][1], accIm[a][2], accIm[a][3]);
                *(float4*)(out + oi + 4) = make_float4(accIm[a][4], accIm[a][5], accIm[a][6], accIm[a][7]);
            }
        }
    }

    // reduce normsq across the 32 tm lanes (within wave half)
    #pragma unroll
    for (int off = 1; off < 32; off <<= 1) {
        #pragma unroll
        for (int a = 0; a < 4; ++a)
            nsq[a] += __shfl_xor(nsq[a], off, 64);
    }
    if (tm == 0) {
        #pragma unroll
        for (int a = 0; a < 4; ++a)
            sScale[4 * tr + a] = 1.f / (sqrtf(nsq[a]) + EPS);
    }
    __syncthreads();

    // -------- phase 4: rescale own writes --------
    for (int ic = 0; ic < 4; ++ic) {
        const int i0 = ic * 256 + 8 * tm;
        #pragma unroll
        for (int a = 0; a < 4; ++a) {
            const int row = 4 * tr + a;
            const float s = sScale[row];
            const long long o = (long long)(row0 + row) * IN_DIM + i0;
            if (o + 8 <= off_im) {
                #pragma unroll
                for (int q = 0; q < 2; ++q) {
                    float4 v = *(float4*)(out + o + 4 * q);
                    v.x *= s; v.y *= s; v.z *= s; v.w *= s;
                    *(float4*)(out + o + 4 * q) = v;
                }
            }
            const long long oi = off_im + o;
            if (oi + 8 <= off_probs) {
                #pragma unroll
                for (int q = 0; q < 2; ++q) {
                    float4 w = *(float4*)(out + oi + 4 * q);
                    w.x *= s; w.y *= s; w.z *= s; w.w *= s;
                    *(float4*)(out + oi + 4 * q) = w;
                }
            }
        }
    }
}

extern "C" void kernel_launch(void* const* d_in, const int* in_sizes, int n_in,
                              void* d_out, int out_size, void* d_ws, size_t ws_size,
                              hipStream_t stream)
{
    const float* psi_re   = (const float*)d_in[0];
    const float* psi_im   = (const float*)d_in[1];
    const float* basis_re = (const float*)d_in[2];
    const float* basis_im = (const float*)d_in[3];

    const long long RIN = (long long)R_TOT * IN_DIM;   // 33,554,432
    const long long RM  = (long long)R_TOT * M_DIM;    //  8,388,608
    const long long cap = (long long)out_size;

    long long off_im, off_probs;
    if (cap == 2 * RIN + RM) {            // planar re/im + probs (75,497,472)
        off_im = RIN; off_probs = 2 * RIN;
    } else if (cap == RIN + RM) {         // real-part-only + probs (41,943,040)
        off_im = RIN; off_probs = RIN;    // imag region width 0 -> guards skip
    } else {                              // fallback: derived planar split
        long long plane = (cap - RM) / 2;
        if (plane < 0) plane = 0;
        off_im = plane; off_probs = 2 * plane;
    }

    povm_kernel<<<R_TOT / TM, 256, 0, stream>>>(psi_re, psi_im, basis_re, basis_im,
                                                (float*)d_out, off_im, off_probs, cap);
}

// Round 2
// 1360.050 us; speedup vs baseline: 1.7489x; 1.6284x over previous
//
#include <hip/hip_runtime.h>
#include <math.h>

#define IN_DIM 1024
#define M_DIM  256
#define R_TOT  32768          // B*S = 8*4096
#define TM     32             // rows per block
#define EPS    1e-12f
#define BSTRIDE 144           // bytes per sB row: 36 dwords -> row base rotates 4 banks/row
                              // -> uniform depth-8 bank access for b128 read AND write, no XOR swizzle

// ---------------------------------------------------------------------------
// Round 2: phase 1 (inner = psi @ conj(basis)) converted to bf16-split MFMA.
//   inner_re = sum_i ps_re*b_re + ps_im*b_im   -> A1 = [re,im] interleaved, K'=2048
//   inner_im = sum_i ps_im*b_re - ps_re*b_im   -> A2 = [im,-re] (rot16 + sign flip of A1)
//   x = x_hi(bf16,trunc) + x_lo(bf16,trunc of exact residual): 3 MFMA passes
//   (Ah*Bh + Ah*Bl + Al*Bh), dropped Al*Bl term ~2^-18 relative.
// MFMA C layout (measured m89): col = lane&15, row = (lane>>4)*4 + reg.
// Phase 2 adapted to that layout (cross-wave rowsum via sRS).
// Phases 3 & 4 byte-identical to round 1.
// ---------------------------------------------------------------------------

typedef __attribute__((ext_vector_type(8))) short s16x8;   // 8 bf16 (4 VGPRs)
typedef __attribute__((ext_vector_type(4))) float f32x4;   // MFMA accumulator

union FragU { int i[4]; int4 i4; s16x8 v; };

#define MFMA16 __builtin_amdgcn_mfma_f32_16x16x32_bf16

__global__ __launch_bounds__(256, 3) void povm_kernel(
    const float* __restrict__ psi_re, const float* __restrict__ psi_im,
    const float* __restrict__ basis_re, const float* __restrict__ basis_im,
    float* __restrict__ out,
    long long off_im,       // float offset of imag plane (== off_probs if none)
    long long off_probs,    // float offset of probs chunk
    long long cap)          // total float capacity (= out_size)
{
    __shared__ __align__(16) char sBmem[M_DIM * BSTRIDE]; // 36864 B; phase1 basis tile, phase3 probs
    __shared__ float sRS[4][TM];                          // per-wave partial row sums
    __shared__ float sScale[TM];

    const int tid  = threadIdx.x;
    const int lane = tid & 63;
    const int w    = tid >> 6;          // wave 0..3 -> m-slab w*64
    const int g    = lane >> 4;         // 0..3 (k'-group)
    const int h16  = lane & 15;         // row (A) / col (B,C) within tile
    const int row0 = blockIdx.x * TM;
    const int mw   = w * 64;

    // staging ids: thread covers (m = it*64 + (tid>>2), i-quad = tid&3)
    const int sq  = tid & 3;
    const int smb = tid >> 2;

    f32x4 accRe[2][4], accIm[2][4];
    #pragma unroll
    for (int rt = 0; rt < 2; ++rt)
        #pragma unroll
        for (int ct = 0; ct < 4; ++ct) {
            accRe[rt][ct] = (f32x4){0.f, 0.f, 0.f, 0.f};
            accIm[rt][ct] = (f32x4){0.f, 0.f, 0.f, 0.f};
        }

    // ===================== phase 1: inner GEMM via MFMA =====================
    for (int ks = 0; ks < 64; ++ks) {
        const int ib = ks * 16;          // i-base of this 32-k' slab

        // ---- A global loads (issue early; L1-served, rows shared by all 4 waves) ----
        float4 ar[2], ai[2];
        #pragma unroll
        for (int rt = 0; rt < 2; ++rt) {
            const size_t off = (size_t)(row0 + rt * 16 + h16) * IN_DIM + ib + g * 4;
            ar[rt] = *(const float4*)(psi_re + off);
            ai[rt] = *(const float4*)(psi_im + off);
        }

        // ---- stage basis slab -> bf16 h/l interleaved [re,im] pairs ----
        #pragma unroll
        for (int it = 0; it < 4; ++it) {
            const int m = it * 64 + smb;
            const size_t boff = (size_t)m * IN_DIM + ib + sq * 4;
            const float4 br = *(const float4*)(basis_re + boff);
            const float4 bi = *(const float4*)(basis_im + boff);
            FragU hf, lf;
            #pragma unroll
            for (int d = 0; d < 4; ++d) {
                const float re = (&br.x)[d], im = (&bi.x)[d];
                const unsigned ur = __float_as_uint(re), ui = __float_as_uint(im);
                hf.i[d] = (int)((ur >> 16) | (ui & 0xFFFF0000u));
                const float lr = re - __uint_as_float(ur & 0xFFFF0000u);
                const float li = im - __uint_as_float(ui & 0xFFFF0000u);
                lf.i[d] = (int)((__float_as_uint(lr) >> 16) |
                                (__float_as_uint(li) & 0xFFFF0000u));
            }
            char* rowp = sBmem + m * BSTRIDE;
            *(int4*)(rowp + 16 * sq)      = hf.i4;   // h half: bytes [0,64)
            *(int4*)(rowp + 64 + 16 * sq) = lf.i4;   // l half: bytes [64,128)
        }
        __syncthreads();

        // ---- build A fragments (register-only) ----
        s16x8 a1h[2], a1l[2], a2h[2], a2l[2];
        #pragma unroll
        for (int rt = 0; rt < 2; ++rt) {
            FragU fh, fl, gh, gl;
            #pragma unroll
            for (int d = 0; d < 4; ++d) {
                const float re = (&ar[rt].x)[d], im = (&ai[rt].x)[d];
                const unsigned ur = __float_as_uint(re), ui = __float_as_uint(im);
                fh.i[d] = (int)((ur >> 16) | (ui & 0xFFFF0000u));
                const float lr = re - __uint_as_float(ur & 0xFFFF0000u);
                const float li = im - __uint_as_float(ui & 0xFFFF0000u);
                fl.i[d] = (int)((__float_as_uint(lr) >> 16) |
                                (__float_as_uint(li) & 0xFFFF0000u));
                // A2 = [im, -re]: rotate 16 then negate new high half
                const unsigned x = (unsigned)fh.i[d];
                gh.i[d] = (int)(((x >> 16) | (x << 16)) ^ 0x80000000u);
                const unsigned y = (unsigned)fl.i[d];
                gl.i[d] = (int)(((y >> 16) | (y << 16)) ^ 0x80000000u);
            }
            a1h[rt] = fh.v; a1l[rt] = fl.v;
            a2h[rt] = gh.v; a2l[rt] = gl.v;
        }

        // ---- MFMA: per column-tile, load B frags then 12 MFMA ----
        #pragma unroll
        for (int ct = 0; ct < 4; ++ct) {
            const char* rowp = sBmem + (mw + ct * 16 + h16) * BSTRIDE;
            const s16x8 bh = *(const s16x8*)(rowp + 16 * g);
            const s16x8 bl = *(const s16x8*)(rowp + 64 + 16 * g);
            #pragma unroll
            for (int rt = 0; rt < 2; ++rt) {
                accRe[rt][ct] = MFMA16(a1h[rt], bh, accRe[rt][ct], 0, 0, 0);
                accRe[rt][ct] = MFMA16(a1h[rt], bl, accRe[rt][ct], 0, 0, 0);
                accRe[rt][ct] = MFMA16(a1l[rt], bh, accRe[rt][ct], 0, 0, 0);
                accIm[rt][ct] = MFMA16(a2h[rt], bh, accIm[rt][ct], 0, 0, 0);
                accIm[rt][ct] = MFMA16(a2h[rt], bl, accIm[rt][ct], 0, 0, 0);
                accIm[rt][ct] = MFMA16(a2l[rt], bh, accIm[rt][ct], 0, 0, 0);
            }
        }
        __syncthreads();
    }

    // ===================== phase 2: p = |inner|^2, probs =====================
    // lane holds inner[row = rt*16 + g*4 + q][m = mw + ct*16 + h16]
    float rs[2][4];
    #pragma unroll
    for (int rt = 0; rt < 2; ++rt)
        #pragma unroll
        for (int q = 0; q < 4; ++q) rs[rt][q] = 0.f;
    #pragma unroll
    for (int rt = 0; rt < 2; ++rt)
        #pragma unroll
        for (int ct = 0; ct < 4; ++ct)
            #pragma unroll
            for (int q = 0; q < 4; ++q) {
                const float p = accRe[rt][ct][q] * accRe[rt][ct][q] +
                                accIm[rt][ct][q] * accIm[rt][ct][q];
                accRe[rt][ct][q] = p;          // accRe now holds p
                rs[rt][q] += p;
            }
    // reduce across the 16 lanes (h16) of each k'-group
    #pragma unroll
    for (int off = 1; off < 16; off <<= 1) {
        #pragma unroll
        for (int rt = 0; rt < 2; ++rt)
            #pragma unroll
            for (int q = 0; q < 4; ++q)
                rs[rt][q] += __shfl_xor(rs[rt][q], off, 64);
    }
    if (h16 == 0) {
        #pragma unroll
        for (int rt = 0; rt < 2; ++rt)
            #pragma unroll
            for (int q = 0; q < 4; ++q)
                sRS[w][rt * 16 + g * 4 + q] = rs[rt][q];
    }
    __syncthreads();
    float inv[2][4];
    #pragma unroll
    for (int rt = 0; rt < 2; ++rt)
        #pragma unroll
        for (int q = 0; q < 4; ++q) {
            const int R = rt * 16 + g * 4 + q;
            inv[rt][q] = 1.f / (sRS[0][R] + sRS[1][R] + sRS[2][R] + sRS[3][R] + EPS);
        }
    float* sProbs = (float*)sBmem;      // aliased: [TM][M_DIM] fp32 (32 KB of 36.9 KB)
    #pragma unroll
    for (int rt = 0; rt < 2; ++rt)
        #pragma unroll
        for (int ct = 0; ct < 4; ++ct)
            #pragma unroll
            for (int q = 0; q < 4; ++q) {
                const float p = accRe[rt][ct][q] * inv[rt][q];
                const int R  = rt * 16 + g * 4 + q;
                const int Mc = mw + ct * 16 + h16;
                sProbs[R * M_DIM + Mc] = p;
                const long long po = off_probs + (long long)(row0 + R) * M_DIM + Mc;
                if (po < cap) out[po] = p;
            }
    __syncthreads();

    // ===================== phase 3: collapsed = probs @ basis (unchanged) =====================
    {
        const int tr = tid >> 5;
        const int tm = tid & 31;
        float aRe[4][8], aIm[4][8];
        float nsq[4] = {0.f, 0.f, 0.f, 0.f};
        for (int ic = 0; ic < 4; ++ic) {
            #pragma unroll
            for (int a = 0; a < 4; ++a)
                #pragma unroll
                for (int b = 0; b < 8; ++b) { aRe[a][b] = 0.f; aIm[a][b] = 0.f; }
            const int i0 = ic * 256 + 8 * tm;
            for (int m = 0; m < M_DIM; ++m) {
                const float* brp = basis_re + (size_t)m * IN_DIM + i0;
                const float* bip = basis_im + (size_t)m * IN_DIM + i0;
                const float4 br0 = *(const float4*)(brp);
                const float4 br1 = *(const float4*)(brp + 4);
                const float4 bi0 = *(const float4*)(bip);
                const float4 bi1 = *(const float4*)(bip + 4);
                const float rv[8] = {br0.x, br0.y, br0.z, br0.w, br1.x, br1.y, br1.z, br1.w};
                const float iv[8] = {bi0.x, bi0.y, bi0.z, bi0.w, bi1.x, bi1.y, bi1.z, bi1.w};
                float pvv[4];
                #pragma unroll
                for (int a = 0; a < 4; ++a) pvv[a] = sProbs[(4 * tr + a) * M_DIM + m];
                #pragma unroll
                for (int a = 0; a < 4; ++a)
                    #pragma unroll
                    for (int b = 0; b < 8; ++b) {
                        aRe[a][b] = fmaf(pvv[a], rv[b], aRe[a][b]);
                        aIm[a][b] = fmaf(pvv[a], iv[b], aIm[a][b]);
                    }
            }
            #pragma unroll
            for (int a = 0; a < 4; ++a) {
                const int row = 4 * tr + a;
                #pragma unroll
                for (int b = 0; b < 8; ++b)
                    nsq[a] += aRe[a][b] * aRe[a][b] + aIm[a][b] * aIm[a][b];
                const long long o = (long long)(row0 + row) * IN_DIM + i0;
                if (o + 8 <= off_im) {                 // real plane region
                    *(float4*)(out + o)     = make_float4(aRe[a][0], aRe[a][1], aRe[a][2], aRe[a][3]);
                    *(float4*)(out + o + 4) = make_float4(aRe[a][4], aRe[a][5], aRe[a][6], aRe[a][7]);
                }
                const long long oi = off_im + o;
                if (oi + 8 <= off_probs) {             // imag plane region (may be width 0)
                    *(float4*)(out + oi)     = make_float4(aIm[a][0], aIm[a][1], aIm[a][2], aIm[a][3]);
                    *(float4*)(out + oi + 4) = make_float4(aIm[a][4], aIm[a][5], aIm[a][6], aIm[a][7]);
                }
            }
        }
        #pragma unroll
        for (int off = 1; off < 32; off <<= 1) {
            #pragma unroll
            for (int a = 0; a < 4; ++a)
                nsq[a] += __shfl_xor(nsq[a], off, 64);
        }
        if (tm == 0) {
            #pragma unroll
            for (int a = 0; a < 4; ++a)
                sScale[4 * tr + a] = 1.f / (sqrtf(nsq[a]) + EPS);
        }
        __syncthreads();

        // -------- phase 4: rescale own writes --------
        for (int ic = 0; ic < 4; ++ic) {
            const int i0 = ic * 256 + 8 * tm;
            #pragma unroll
            for (int a = 0; a < 4; ++a) {
                const int row = 4 * tr + a;
                const float s = sScale[row];
                const long long o = (long long)(row0 + row) * IN_DIM + i0;
                if (o + 8 <= off_im) {
                    #pragma unroll
                    for (int q = 0; q < 2; ++q) {
                        float4 v = *(float4*)(out + o + 4 * q);
                        v.x *= s; v.y *= s; v.z *= s; v.w *= s;
                        *(float4*)(out + o + 4 * q) = v;
                    }
                }
                const long long oi = off_im + o;
                if (oi + 8 <= off_probs) {
                    #pragma unroll
                    for (int q = 0; q < 2; ++q) {
                        float4 vw = *(float4*)(out + oi + 4 * q);
                        vw.x *= s; vw.y *= s; vw.z *= s; vw.w *= s;
                        *(float4*)(out + oi + 4 * q) = vw;
                    }
                }
            }
        }
    }
}

extern "C" void kernel_launch(void* const* d_in, const int* in_sizes, int n_in,
                              void* d_out, int out_size, void* d_ws, size_t ws_size,
                              hipStream_t stream)
{
    const float* psi_re   = (const float*)d_in[0];
    const float* psi_im   = (const float*)d_in[1];
    const float* basis_re = (const float*)d_in[2];
    const float* basis_im = (const float*)d_in[3];

    const long long RIN = (long long)R_TOT * IN_DIM;   // 33,554,432
    const long long RM  = (long long)R_TOT * M_DIM;    //  8,388,608
    const long long cap = (long long)out_size;

    long long off_im, off_probs;
    if (cap == 2 * RIN + RM) {            // planar re/im + probs (75,497,472)
        off_im = RIN; off_probs = 2 * RIN;
    } else if (cap == RIN + RM) {         // real-part-only + probs (41,943,040)
        off_im = RIN; off_probs = RIN;    // imag region width 0 -> guards skip
    } else {                              // fallback: derived planar split
        long long plane = (cap - RM) / 2;
        if (plane < 0) plane = 0;
        off_im = plane; off_probs = 2 * plane;
    }

    povm_kernel<<<R_TOT / TM, 256, 0, stream>>>(psi_re, psi_im, basis_re, basis_im,
                                                (float*)d_out, off_im, off_probs, cap);
}

// Round 3
// 972.032 us; speedup vs baseline: 2.4470x; 1.3992x over previous
//
#include <hip/hip_runtime.h>
#include <math.h>

#define IN_DIM 1024
#define M_DIM  256
#define R_TOT  32768          // B*S = 8*4096
#define TM     32             // rows per block
#define EPS    1e-12f
#define BSTRIDE 144           // phase-1 sB row stride (bank-rotating, validated r2)
#define PROW   1040           // sProbsHL row stride bytes: [h 512][l 512][pad 16]

// ---------------------------------------------------------------------------
// Round 3: phase 3 (collapsed = probs @ basis) converted to MFMA.
//  - A = probs, split h/l bf16 in phase 2 (registers) -> LDS sProbsHL.
//    A-frag = ds_read_b128, banks 4*(h16+g) mod 32 -> uniform depth 8, clean.
//  - B = basis, read DIRECT from global per frag: 8 loads basis[m..][col],
//    col = lane-contiguous -> coalesced, L2-served; packed via
//    v_cvt_pk_bf16_f32 (1 inst / 2 elems). No LDS tile, no syncthreads:
//    phase-3 waves fully independent.
//  - 2 passes: Ah*B + Al*B (B single RTN bf16; err std ~3.6e-5 on output).
// Phase 1 identical to round 2 (validated). Phase 2 numerics identical
// (adds bf16 h/l LDS park). Phase 4 identical.
// LDS: sMem 36864 (phase-1 tile, aliased by sProbsHL 33280 in ph2/3).
// ---------------------------------------------------------------------------

typedef __attribute__((ext_vector_type(8))) short s16x8;   // 8 bf16 (4 VGPRs)
typedef __attribute__((ext_vector_type(4))) float f32x4;   // MFMA accumulator

union FragU { int i[4]; int4 i4; s16x8 v; };

#define MFMA16 __builtin_amdgcn_mfma_f32_16x16x32_bf16

__device__ __forceinline__ int cvt_pk_bf16(float lo, float hi) {
    int r;
    asm("v_cvt_pk_bf16_f32 %0, %1, %2" : "=v"(r) : "v"(lo), "v"(hi));
    return r;
}
__device__ __forceinline__ unsigned short rtn_bf16(float x) {
    unsigned u = __float_as_uint(x);
    return (unsigned short)((u + 0x7FFFu + ((u >> 16) & 1u)) >> 16);
}

__global__ __launch_bounds__(256, 3) void povm_kernel(
    const float* __restrict__ psi_re, const float* __restrict__ psi_im,
    const float* __restrict__ basis_re, const float* __restrict__ basis_im,
    float* __restrict__ out,
    long long off_im,       // float offset of imag plane (== off_probs if none)
    long long off_probs,    // float offset of probs chunk
    long long cap)          // total float capacity (= out_size)
{
    __shared__ __align__(16) char sMem[M_DIM * BSTRIDE]; // 36864 B: ph1 B-tile, then sProbsHL
    __shared__ float sRS[4][TM];                         // ph2 rowsums; ph3 nsq partials
    __shared__ float sScale[TM];

    const int tid  = threadIdx.x;
    const int lane = tid & 63;
    const int w    = tid >> 6;          // wave 0..3
    const int g    = lane >> 4;         // 0..3 (k-group)
    const int h16  = lane & 15;         // row (A) / col (B,C) within tile
    const int row0 = blockIdx.x * TM;
    const int mw   = w * 64;            // phase-1 m-slab

    // staging ids (phase 1): thread covers (m = it*64 + (tid>>2), i-quad = tid&3)
    const int sq  = tid & 3;
    const int smb = tid >> 2;

    f32x4 accRe[2][4], accIm[2][4];
    #pragma unroll
    for (int rt = 0; rt < 2; ++rt)
        #pragma unroll
        for (int ct = 0; ct < 4; ++ct) {
            accRe[rt][ct] = (f32x4){0.f, 0.f, 0.f, 0.f};
            accIm[rt][ct] = (f32x4){0.f, 0.f, 0.f, 0.f};
        }

    // ===================== phase 1: inner GEMM via MFMA (unchanged) =====================
    for (int ks = 0; ks < 64; ++ks) {
        const int ib = ks * 16;          // i-base of this 32-k' slab

        float4 ar[2], ai[2];
        #pragma unroll
        for (int rt = 0; rt < 2; ++rt) {
            const size_t off = (size_t)(row0 + rt * 16 + h16) * IN_DIM + ib + g * 4;
            ar[rt] = *(const float4*)(psi_re + off);
            ai[rt] = *(const float4*)(psi_im + off);
        }

        #pragma unroll
        for (int it = 0; it < 4; ++it) {
            const int m = it * 64 + smb;
            const size_t boff = (size_t)m * IN_DIM + ib + sq * 4;
            const float4 br = *(const float4*)(basis_re + boff);
            const float4 bi = *(const float4*)(basis_im + boff);
            FragU hf, lf;
            #pragma unroll
            for (int d = 0; d < 4; ++d) {
                const float re = (&br.x)[d], im = (&bi.x)[d];
                const unsigned ur = __float_as_uint(re), ui = __float_as_uint(im);
                hf.i[d] = (int)((ur >> 16) | (ui & 0xFFFF0000u));
                const float lr = re - __uint_as_float(ur & 0xFFFF0000u);
                const float li = im - __uint_as_float(ui & 0xFFFF0000u);
                lf.i[d] = (int)((__float_as_uint(lr) >> 16) |
                                (__float_as_uint(li) & 0xFFFF0000u));
            }
            char* rowp = sMem + m * BSTRIDE;
            *(int4*)(rowp + 16 * sq)      = hf.i4;   // h half: bytes [0,64)
            *(int4*)(rowp + 64 + 16 * sq) = lf.i4;   // l half: bytes [64,128)
        }
        __syncthreads();

        s16x8 a1h[2], a1l[2], a2h[2], a2l[2];
        #pragma unroll
        for (int rt = 0; rt < 2; ++rt) {
            FragU fh, fl, gh, gl;
            #pragma unroll
            for (int d = 0; d < 4; ++d) {
                const float re = (&ar[rt].x)[d], im = (&ai[rt].x)[d];
                const unsigned ur = __float_as_uint(re), ui = __float_as_uint(im);
                fh.i[d] = (int)((ur >> 16) | (ui & 0xFFFF0000u));
                const float lr = re - __uint_as_float(ur & 0xFFFF0000u);
                const float li = im - __uint_as_float(ui & 0xFFFF0000u);
                fl.i[d] = (int)((__float_as_uint(lr) >> 16) |
                                (__float_as_uint(li) & 0xFFFF0000u));
                const unsigned x = (unsigned)fh.i[d];
                gh.i[d] = (int)(((x >> 16) | (x << 16)) ^ 0x80000000u);
                const unsigned y = (unsigned)fl.i[d];
                gl.i[d] = (int)(((y >> 16) | (y << 16)) ^ 0x80000000u);
            }
            a1h[rt] = fh.v; a1l[rt] = fl.v;
            a2h[rt] = gh.v; a2l[rt] = gl.v;
        }

        #pragma unroll
        for (int ct = 0; ct < 4; ++ct) {
            const char* rowp = sMem + (mw + ct * 16 + h16) * BSTRIDE;
            const s16x8 bh = *(const s16x8*)(rowp + 16 * g);
            const s16x8 bl = *(const s16x8*)(rowp + 64 + 16 * g);
            #pragma unroll
            for (int rt = 0; rt < 2; ++rt) {
                accRe[rt][ct] = MFMA16(a1h[rt], bh, accRe[rt][ct], 0, 0, 0);
                accRe[rt][ct] = MFMA16(a1h[rt], bl, accRe[rt][ct], 0, 0, 0);
                accRe[rt][ct] = MFMA16(a1l[rt], bh, accRe[rt][ct], 0, 0, 0);
                accIm[rt][ct] = MFMA16(a2h[rt], bh, accIm[rt][ct], 0, 0, 0);
                accIm[rt][ct] = MFMA16(a2h[rt], bl, accIm[rt][ct], 0, 0, 0);
                accIm[rt][ct] = MFMA16(a2l[rt], bh, accIm[rt][ct], 0, 0, 0);
            }
        }
        __syncthreads();
    }

    // ===================== phase 2: p = |inner|^2, probs =====================
    float rs[2][4];
    #pragma unroll
    for (int rt = 0; rt < 2; ++rt)
        #pragma unroll
        for (int q = 0; q < 4; ++q) rs[rt][q] = 0.f;
    #pragma unroll
    for (int rt = 0; rt < 2; ++rt)
        #pragma unroll
        for (int ct = 0; ct < 4; ++ct)
            #pragma unroll
            for (int q = 0; q < 4; ++q) {
                const float p = accRe[rt][ct][q] * accRe[rt][ct][q] +
                                accIm[rt][ct][q] * accIm[rt][ct][q];
                accRe[rt][ct][q] = p;
                rs[rt][q] += p;
            }
    #pragma unroll
    for (int off = 1; off < 16; off <<= 1) {
        #pragma unroll
        for (int rt = 0; rt < 2; ++rt)
            #pragma unroll
            for (int q = 0; q < 4; ++q)
                rs[rt][q] += __shfl_xor(rs[rt][q], off, 64);
    }
    if (h16 == 0) {
        #pragma unroll
        for (int rt = 0; rt < 2; ++rt)
            #pragma unroll
            for (int q = 0; q < 4; ++q)
                sRS[w][rt * 16 + g * 4 + q] = rs[rt][q];
    }
    __syncthreads();
    float inv[2][4];
    #pragma unroll
    for (int rt = 0; rt < 2; ++rt)
        #pragma unroll
        for (int q = 0; q < 4; ++q) {
            const int R = rt * 16 + g * 4 + q;
            inv[rt][q] = 1.f / (sRS[0][R] + sRS[1][R] + sRS[2][R] + sRS[3][R] + EPS);
        }
    // store probs fp32 to global + bf16 h/l to sProbsHL (aliases dead ph1 tile)
    #pragma unroll
    for (int rt = 0; rt < 2; ++rt)
        #pragma unroll
        for (int ct = 0; ct < 4; ++ct)
            #pragma unroll
            for (int q = 0; q < 4; ++q) {
                const float p = accRe[rt][ct][q] * inv[rt][q];
                const int R  = rt * 16 + g * 4 + q;
                const int Mc = mw + ct * 16 + h16;
                const unsigned short ph = rtn_bf16(p);
                const float phf = __uint_as_float((unsigned)ph << 16);
                const unsigned short pl = rtn_bf16(p - phf);
                *(unsigned short*)(sMem + R * PROW + 2 * Mc)       = ph;
                *(unsigned short*)(sMem + R * PROW + 512 + 2 * Mc) = pl;
                const long long po = off_probs + (long long)(row0 + R) * M_DIM + Mc;
                if (po < cap) out[po] = p;
            }
    __syncthreads();

    // ===================== phase 3: collapsed = probs @ basis via MFMA =====================
    {
        const int wi0 = w * 256;            // wave-private i range: no barriers in loop
        float nsqp[2][4];
        #pragma unroll
        for (int rt = 0; rt < 2; ++rt)
            #pragma unroll
            for (int q = 0; q < 4; ++q) nsqp[rt][q] = 0.f;

        for (int ibk = 0; ibk < 4; ++ibk) {
            const int ibase = wi0 + ibk * 64;
            f32x4 cRe[2][4], cIm[2][4];
            #pragma unroll
            for (int rt = 0; rt < 2; ++rt)
                #pragma unroll
                for (int nt = 0; nt < 4; ++nt) {
                    cRe[rt][nt] = (f32x4){0.f, 0.f, 0.f, 0.f};
                    cIm[rt][nt] = (f32x4){0.f, 0.f, 0.f, 0.f};
                }
            for (int ks = 0; ks < 8; ++ks) {
                s16x8 ah[2], al[2];
                #pragma unroll
                for (int rt = 0; rt < 2; ++rt) {
                    const char* rp = sMem + (rt * 16 + h16) * PROW + ks * 64 + 16 * g;
                    ah[rt] = *(const s16x8*)(rp);
                    al[rt] = *(const s16x8*)(rp + 512);
                }
                const int mrow = ks * 32 + 8 * g;       // k-slot base: matches A-frag k map
                #pragma unroll
                for (int nt = 0; nt < 4; ++nt) {
                    const int col = ibase + nt * 16 + h16;
                    const float* pr = basis_re + (size_t)mrow * IN_DIM + col;
                    const float* pi = basis_im + (size_t)mrow * IN_DIM + col;
                    FragU bR, bI;
                    #pragma unroll
                    for (int d = 0; d < 4; ++d) {
                        bR.i[d] = cvt_pk_bf16(pr[(size_t)(2 * d) * IN_DIM],
                                              pr[(size_t)(2 * d + 1) * IN_DIM]);
                        bI.i[d] = cvt_pk_bf16(pi[(size_t)(2 * d) * IN_DIM],
                                              pi[(size_t)(2 * d + 1) * IN_DIM]);
                    }
                    #pragma unroll
                    for (int rt = 0; rt < 2; ++rt) {
                        cRe[rt][nt] = MFMA16(ah[rt], bR.v, cRe[rt][nt], 0, 0, 0);
                        cRe[rt][nt] = MFMA16(al[rt], bR.v, cRe[rt][nt], 0, 0, 0);
                        cIm[rt][nt] = MFMA16(ah[rt], bI.v, cIm[rt][nt], 0, 0, 0);
                        cIm[rt][nt] = MFMA16(al[rt], bI.v, cIm[rt][nt], 0, 0, 0);
                    }
                }
            }
            // epilogue: nsq partials + unscaled store (C layout: row=4g+q, col=h16)
            #pragma unroll
            for (int rt = 0; rt < 2; ++rt)
                #pragma unroll
                for (int nt = 0; nt < 4; ++nt) {
                    const int col = ibase + nt * 16 + h16;
                    #pragma unroll
                    for (int q = 0; q < 4; ++q) {
                        const float vr = cRe[rt][nt][q], vi = cIm[rt][nt][q];
                        nsqp[rt][q] += vr * vr + vi * vi;
                        const int row = rt * 16 + 4 * g + q;
                        const long long o = (long long)(row0 + row) * IN_DIM + col;
                        if (o < off_im) out[o] = vr;
                        const long long oi = off_im + o;
                        if (oi < off_probs) out[oi] = vi;
                    }
                }
        }
        // reduce nsq over the 16 h16 lanes; publish per-wave partials
        #pragma unroll
        for (int off = 1; off < 16; off <<= 1) {
            #pragma unroll
            for (int rt = 0; rt < 2; ++rt)
                #pragma unroll
                for (int q = 0; q < 4; ++q)
                    nsqp[rt][q] += __shfl_xor(nsqp[rt][q], off, 64);
        }
        if (h16 == 0) {
            #pragma unroll
            for (int rt = 0; rt < 2; ++rt)
                #pragma unroll
                for (int q = 0; q < 4; ++q)
                    sRS[w][rt * 16 + 4 * g + q] = nsqp[rt][q];
        }
        __syncthreads();
        if (tid < TM)
            sScale[tid] = 1.f / (sqrtf(sRS[0][tid] + sRS[1][tid] +
                                       sRS[2][tid] + sRS[3][tid]) + EPS);
        __syncthreads();
    }

    // ===================== phase 4: rescale own writes (unchanged) =====================
    {
        const int tr = tid >> 5;
        const int tm = tid & 31;
        for (int ic = 0; ic < 4; ++ic) {
            const int i0 = ic * 256 + 8 * tm;
            #pragma unroll
            for (int a = 0; a < 4; ++a) {
                const int row = 4 * tr + a;
                const float s = sScale[row];
                const long long o = (long long)(row0 + row) * IN_DIM + i0;
                if (o + 8 <= off_im) {
                    #pragma unroll
                    for (int q = 0; q < 2; ++q) {
                        float4 v = *(float4*)(out + o + 4 * q);
                        v.x *= s; v.y *= s; v.z *= s; v.w *= s;
                        *(float4*)(out + o + 4 * q) = v;
                    }
                }
                const long long oi = off_im + o;
                if (oi + 8 <= off_probs) {
                    #pragma unroll
                    for (int q = 0; q < 2; ++q) {
                        float4 vw = *(float4*)(out + oi + 4 * q);
                        vw.x *= s; vw.y *= s; vw.z *= s; vw.w *= s;
                        *(float4*)(out + oi + 4 * q) = vw;
                    }
                }
            }
        }
    }
}

extern "C" void kernel_launch(void* const* d_in, const int* in_sizes, int n_in,
                              void* d_out, int out_size, void* d_ws, size_t ws_size,
                              hipStream_t stream)
{
    const float* psi_re   = (const float*)d_in[0];
    const float* psi_im   = (const float*)d_in[1];
    const float* basis_re = (const float*)d_in[2];
    const float* basis_im = (const float*)d_in[3];

    const long long RIN = (long long)R_TOT * IN_DIM;   // 33,554,432
    const long long RM  = (long long)R_TOT * M_DIM;    //  8,388,608
    const long long cap = (long long)out_size;

    long long off_im, off_probs;
    if (cap == 2 * RIN + RM) {            // planar re/im + probs (75,497,472)
        off_im = RIN; off_probs = 2 * RIN;
    } else if (cap == RIN + RM) {         // real-part-only + probs (41,943,040)
        off_im = RIN; off_probs = RIN;    // imag region width 0 -> guards skip
    } else {                              // fallback: derived planar split
        long long plane = (cap - RM) / 2;
        if (plane < 0) plane = 0;
        off_im = plane; off_probs = 2 * plane;
    }

    povm_kernel<<<R_TOT / TM, 256, 0, stream>>>(psi_re, psi_im, basis_re, basis_im,
                                                (float*)d_out, off_im, off_probs, cap);
}